// Round 3
// baseline (249.726 us; speedup 1.0000x reference)
//
#include <hip/hip_runtime.h>

#define N_NODES 50000
#define N_EDGES 800000
#define N_GRAPHS 256
#define F 64
#define NBUCK 196          // ceil(50000/256) coarse buckets (dst>>8)
#define CAP 5120           // per-bucket capacity incl. 4-align padding
#define P3_TILE 2048
#define P3_GRID ((N_EDGES + P3_TILE - 1) / P3_TILE)
#define BCAP 6144
#define ZOFF (N_NODES * 128) // byte offset of the zero row in Hn
#define NSLOT (NBUCK * 256)  // 50176 permuted node slots (incl. pad slots)

// ---- bf16 helpers (RTN), all math stays f32 ----
__device__ __forceinline__ unsigned short f2bf(float f) {
    union { float f; unsigned u; } c; c.f = f;
    unsigned u = c.u + 0x7FFFu + ((c.u >> 16) & 1u);
    return (unsigned short)(u >> 16);
}
__device__ __forceinline__ unsigned pack2bf(float lo, float hi) {
    return (unsigned)f2bf(lo) | ((unsigned)f2bf(hi) << 16);
}
__device__ __forceinline__ float bfl(unsigned u) {
    union { unsigned u; float f; } c; c.u = u << 16; return c.f;
}
__device__ __forceinline__ float bfh(unsigned u) {
    union { unsigned u; float f; } c; c.u = u & 0xFFFF0000u; return c.f;
}

// ---- depth-2 software-pipelined gather over one node's padded edge run ----
__device__ __forceinline__ void gather_run(const int* __restrict__ eidx,
                                           const char* __restrict__ Hb,
                                           int beg, int end, int fo, float* a) {
#pragma unroll
    for (int i = 0; i < 8; ++i) a[i] = 0.f;
    int kb = (beg < end) ? beg : 0;          // always-valid descriptor slot
    int4 oc = *(const int4*)(eidx + kb);
    int k1 = beg + 4;
    int k1c = (k1 < end) ? k1 : kb;
    int4 on = *(const int4*)(eidx + k1c);
    uint4 pc = *(const uint4*)(Hb + oc.x + fo);
    uint4 qc = *(const uint4*)(Hb + oc.y + fo);
    uint4 rc = *(const uint4*)(Hb + oc.z + fo);
    uint4 wc = *(const uint4*)(Hb + oc.w + fo);
    for (int k = beg; k < end; k += 4) {
        int k2 = k + 8;
        int k2c = (k2 < end) ? k2 : kb;
        int4 of = *(const int4*)(eidx + k2c);
        uint4 pn = *(const uint4*)(Hb + on.x + fo);
        uint4 qn = *(const uint4*)(Hb + on.y + fo);
        uint4 rn = *(const uint4*)(Hb + on.z + fo);
        uint4 wn = *(const uint4*)(Hb + on.w + fo);
        a[0] += (bfl(pc.x) + bfl(qc.x)) + (bfl(rc.x) + bfl(wc.x));
        a[1] += (bfh(pc.x) + bfh(qc.x)) + (bfh(rc.x) + bfh(wc.x));
        a[2] += (bfl(pc.y) + bfl(qc.y)) + (bfl(rc.y) + bfl(wc.y));
        a[3] += (bfh(pc.y) + bfh(qc.y)) + (bfh(rc.y) + bfh(wc.y));
        a[4] += (bfl(pc.z) + bfl(qc.z)) + (bfl(rc.z) + bfl(wc.z));
        a[5] += (bfh(pc.z) + bfh(qc.z)) + (bfh(rc.z) + bfh(wc.z));
        a[6] += (bfl(pc.w) + bfl(qc.w)) + (bfl(rc.w) + bfl(wc.w));
        a[7] += (bfh(pc.w) + bfh(qc.w)) + (bfh(rc.w) + bfh(wc.w));
        oc = on; on = of;
        pc = pn; qc = qn; rc = rn; wc = wn;
    }
}

// ---------------- P1: partition edges into fixed-capacity buckets ----------------
__global__ __launch_bounds__(256) void partition_edges(const int* __restrict__ src,
                                                       const int* __restrict__ dst,
                                                       int* __restrict__ bcur,
                                                       unsigned int* __restrict__ bpair) {
    __shared__ int bh[NBUCK], bloc[NBUCK], bpos[NBUCK];
    int t = threadIdx.x;
    int lo = blockIdx.x * P3_TILE;
    int hi = min(lo + P3_TILE, N_EDGES);
    for (int i = t; i < NBUCK; i += 256) { bh[i] = 0; bpos[i] = 0; }
    __syncthreads();
    for (int e = lo + t; e < hi; e += 256) atomicAdd(&bh[dst[e] >> 8], 1);
    __syncthreads();
    for (int i = t; i < NBUCK; i += 256)
        bloc[i] = bh[i] ? atomicAdd(&bcur[i], bh[i]) : 0;
    __syncthreads();
    for (int e = lo + t; e < hi; e += 256) {
        int d = dst[e];
        int b = d >> 8;
        int r = atomicAdd(&bpos[b], 1);
        bpair[(size_t)b * CAP + bloc[b] + r] = ((unsigned)src[e] << 8) | (unsigned)(d & 255);
    }
}

// ---------------- P2: per-bucket counting sort -> 4-aligned padded CSR ----------------
// Also builds ord[]: per-bucket node permutation sorted by iteration count
// (pv>>2), so gather waves get 8 similar-degree nodes (balanced trip counts).
__global__ __launch_bounds__(256) void bucket_sort(const unsigned int* __restrict__ bpair,
                                                   const int* __restrict__ bcur,
                                                   int* __restrict__ eidx,
                                                   int* __restrict__ rbeg,
                                                   int* __restrict__ rend,
                                                   float* __restrict__ dinv,
                                                   int* __restrict__ ord,
                                                   unsigned short* __restrict__ Abf,
                                                   unsigned short* __restrict__ Bbf) {
    __shared__ int cnt[256], s[256], pos[256];
    __shared__ int dhist[64], dscan[64];
    __shared__ int lout[BCAP];
    int b = blockIdx.x, t = threadIdx.x;
    int base = b * CAP;
    int sz = bcur[b];

    if (b == 0 && t < 8) {
        ((uint4*)Abf)[(size_t)N_NODES * 8 + t] = make_uint4(0u, 0u, 0u, 0u);
        ((uint4*)Bbf)[(size_t)N_NODES * 8 + t] = make_uint4(0u, 0u, 0u, 0u);
    }

    cnt[t] = 0;
    if (t < 64) dhist[t] = 0;
    __syncthreads();
    for (int i = t; i < sz; i += 256) atomicAdd(&cnt[bpair[base + i] & 255], 1);
    __syncthreads();
    int v = cnt[t];
    int pv = (v + 3) & ~3;          // padded to multiple of 4
    s[t] = pv;
    int ic = min(pv >> 2, 63);      // iteration-count bin for degree sort
    int myoff = atomicAdd(&dhist[ic], 1);
    __syncthreads();
    for (int off = 1; off < 256; off <<= 1) {
        int u = (t >= off) ? s[t - off] : 0;
        __syncthreads();
        s[t] += u;
        __syncthreads();
    }
    int excl = s[t] - pv;            // padded exclusive prefix
    pos[t] = excl;
    int node = b * 256 + t;
    if (node < N_NODES) {
        rbeg[node] = base + excl;
        rend[node] = base + excl + pv;                 // padded end (loop bound)
        dinv[node] = 1.0f / sqrtf((float)v + 1.0f);    // actual degree +1 self-loop
    }
    int padtot = s[255];             // total padded size of this bucket

    // ---- degree-sort permutation: inclusive scan of dhist -> rank ----
    if (t < 64) dscan[t] = dhist[t];
    __syncthreads();
    for (int off = 1; off < 64; off <<= 1) {
        int u = (t >= off && t < 64) ? dscan[t - off] : 0;
        __syncthreads();
        if (t < 64) dscan[t] += u;
        __syncthreads();
    }
    int rank = dscan[ic] - dhist[ic] + myoff;   // exclusive base + offset in bin
    ord[b * 256 + rank] = node;                 // pad nodes (>=N_NODES) included

    // scatter actual edges
    for (int i = t; i < sz; i += 256) {
        unsigned p = bpair[base + i];
        int r = atomicAdd(&pos[p & 255], 1);
        lout[r] = (int)((p >> 8) << 7);   // src byte offset (src*128, bf16 row)
    }
    __syncthreads();
    // fill pad slots with zero-row sentinel (each thread pads its own node run)
    for (int j = v; j < pv; j++) lout[excl + j] = ZOFF;
    __syncthreads();
    for (int i = t; i < padtot; i += 256) eidx[base + i] = lout[i];
}

// ---------------- GEMM + dinv fold: Hn[i,:] = bf16( (X[i,:] @ W) * dinv[i] ) ----------------
#define XSTRIDE 17
__global__ __launch_bounds__(256) void gemm64_f32(const float* __restrict__ X,
                                                  const float* __restrict__ W,
                                                  const float* __restrict__ dinv,
                                                  unsigned short* __restrict__ Hn, int n) {
    __shared__ float4 sW[64 * 16];
    __shared__ float4 sX[128 * XSTRIDE];
    int tid = threadIdx.x;
    int base = blockIdx.x * 128;

    const float4* W4 = (const float4*)W;
    for (int i = tid; i < 64 * 16; i += 256) sW[i] = W4[i];
    {
        const float4* X4 = (const float4*)X;
        for (int i = tid; i < 128 * 16; i += 256) {
            int r = i >> 4, kg = i & 15;
            int node = base + r;
            sX[r * XSTRIDE + kg] = (node < n) ? X4[(size_t)node * 16 + kg]
                                              : make_float4(0.f, 0.f, 0.f, 0.f);
        }
    }
    __syncthreads();

    int fg = tid & 15;
    int ng = tid >> 4;
    float4 acc[8];
#pragma unroll
    for (int ii = 0; ii < 8; ii++) acc[ii] = make_float4(0.f, 0.f, 0.f, 0.f);

    for (int kg = 0; kg < 16; kg++) {
        float4 xv[8];
#pragma unroll
        for (int ii = 0; ii < 8; ii++) xv[ii] = sX[(ng + 16 * ii) * XSTRIDE + kg];
#pragma unroll
        for (int kk = 0; kk < 4; kk++) {
            float4 wv = sW[(4 * kg + kk) * 16 + fg];
#pragma unroll
            for (int ii = 0; ii < 8; ii++) {
                float xs = (kk == 0) ? xv[ii].x : (kk == 1) ? xv[ii].y
                         : (kk == 2) ? xv[ii].z : xv[ii].w;
                acc[ii].x += wv.x * xs;
                acc[ii].y += wv.y * xs;
                acc[ii].z += wv.z * xs;
                acc[ii].w += wv.w * xs;
            }
        }
    }

    ushort4* H4 = (ushort4*)Hn;
#pragma unroll
    for (int ii = 0; ii < 8; ii++) {
        int node = base + ng + 16 * ii;
        if (node < n) {
            float d = dinv[node];
            float4 o = acc[ii];
            ushort4 u;
            u.x = f2bf(o.x * d); u.y = f2bf(o.y * d);
            u.z = f2bf(o.z * d); u.w = f2bf(o.w * d);
            H4[(size_t)node * 16 + fg] = u;
        }
    }
}

// ---------------- fused gather + next-layer GEMM (layers 1->2, 2->3) ----------------
// Node assignment via ord[] (degree-sorted) so the 8 lane-groups of a wave have
// balanced trip counts (max ~= mean instead of max-of-8).
__global__ __launch_bounds__(256) void gather_gemm(const int* __restrict__ ord,
                                                   const int* __restrict__ rbeg,
                                                   const int* __restrict__ rend,
                                                   const int* __restrict__ eidx,
                                                   const float* __restrict__ dinv,
                                                   const unsigned short* __restrict__ Hin,
                                                   const float* __restrict__ bias,
                                                   const float* __restrict__ W,
                                                   unsigned short* __restrict__ Hout) {
    __shared__ float4 sW[64 * 16];
    const float4* W4 = (const float4*)W;
    for (int i = threadIdx.x; i < 64 * 16; i += 256) sW[i] = W4[i];
    __syncthreads();

    int wv = (blockIdx.x * blockDim.x + threadIdx.x) >> 6;
    int lane = threadIdx.x & 63;
    int ns = lane >> 3, f = lane & 7;
    int node = ord[wv * 8 + ns];        // grid covers NSLOT slots exactly
    bool valid = node < N_NODES;
    int nodec = valid ? node : 0;
    int beg = valid ? rbeg[nodec] : 0;
    int end = valid ? rend[nodec] : 0;
    const char* Hb = (const char*)Hin;

    // hoist independent epilogue loads above the latency-bound loop
    float di = dinv[nodec];
    uint4 hs = *(const uint4*)(Hb + (size_t)nodec * 128 + f * 16);
    float4 bb0 = ((const float4*)bias)[2 * f];
    float4 bb1 = ((const float4*)bias)[2 * f + 1];

    float a[8];
    gather_run(eidx, Hb, beg, end, f * 16, a);

    float v[8];
    v[0] = fmaxf(di * (a[0] + bfl(hs.x)) + bb0.x, 0.f);
    v[1] = fmaxf(di * (a[1] + bfh(hs.x)) + bb0.y, 0.f);
    v[2] = fmaxf(di * (a[2] + bfl(hs.y)) + bb0.z, 0.f);
    v[3] = fmaxf(di * (a[3] + bfh(hs.y)) + bb0.w, 0.f);
    v[4] = fmaxf(di * (a[4] + bfl(hs.z)) + bb1.x, 0.f);
    v[5] = fmaxf(di * (a[5] + bfh(hs.z)) + bb1.y, 0.f);
    v[6] = fmaxf(di * (a[6] + bfl(hs.w)) + bb1.z, 0.f);
    v[7] = fmaxf(di * (a[7] + bfh(hs.w)) + bb1.w, 0.f);

    // y[8f..8f+7] = sum_k h[k] * W[k][8f..8f+7]; h[8c+j] lives in lane (ns*8+c).v[j]
    float y0 = 0.f, y1 = 0.f, y2 = 0.f, y3 = 0.f;
    float y4 = 0.f, y5 = 0.f, y6 = 0.f, y7 = 0.f;
    int pb = (lane & 56) << 2;        // byte addr of this node's lane-group base
#pragma unroll
    for (int c = 0; c < 8; ++c) {
        int ad = pb + 4 * c;
#pragma unroll
        for (int j = 0; j < 8; ++j) {
            float hk = __int_as_float(
                __builtin_amdgcn_ds_bpermute(ad, __float_as_int(v[j])));
            float4 w0 = sW[(8 * c + j) * 16 + 2 * f];
            float4 w1 = sW[(8 * c + j) * 16 + 2 * f + 1];
            y0 += hk * w0.x; y1 += hk * w0.y; y2 += hk * w0.z; y3 += hk * w0.w;
            y4 += hk * w1.x; y5 += hk * w1.y; y6 += hk * w1.z; y7 += hk * w1.w;
        }
    }

    if (valid) {
        uint4 u;
        u.x = pack2bf(y0 * di, y1 * di);
        u.y = pack2bf(y2 * di, y3 * di);
        u.z = pack2bf(y4 * di, y5 * di);
        u.w = pack2bf(y6 * di, y7 * di);
        ((uint4*)Hout)[(size_t)node * 8 + f] = u;
    }
}

// ---------------- layer-3 gather fused with pooling dot: writes pdot[node] ----------------
__global__ __launch_bounds__(256) void gather_pool(const int* __restrict__ ord,
                                                   const int* __restrict__ rbeg,
                                                   const int* __restrict__ rend,
                                                   const int* __restrict__ eidx,
                                                   const float* __restrict__ dinv,
                                                   const unsigned short* __restrict__ Hn,
                                                   const float* __restrict__ b,
                                                   const float* __restrict__ Wl,
                                                   float* __restrict__ pdot) {
    int wv = (blockIdx.x * blockDim.x + threadIdx.x) >> 6;
    int lane = threadIdx.x & 63;
    int ns = lane >> 3, f = lane & 7;
    int node = ord[wv * 8 + ns];
    bool valid = node < N_NODES;
    int nodec = valid ? node : 0;
    int beg = valid ? rbeg[nodec] : 0;
    int end = valid ? rend[nodec] : 0;
    const char* Hb = (const char*)Hn;

    // hoist independent epilogue loads above the loop (clamped addresses)
    float di = valid ? dinv[nodec] : 0.f;
    uint4 hs = *(const uint4*)(Hb + (size_t)nodec * 128 + f * 16);
    float4 b0 = ((const float4*)b)[2 * f];
    float4 b1 = ((const float4*)b)[2 * f + 1];
    float4 w0 = ((const float4*)Wl)[2 * f];
    float4 w1 = ((const float4*)Wl)[2 * f + 1];

    float a[8];
    gather_run(eidx, Hb, beg, end, f * 16, a);

    float d = 0.f;
    d += fmaxf(di * (a[0] + bfl(hs.x)) + b0.x, 0.f) * w0.x;
    d += fmaxf(di * (a[1] + bfh(hs.x)) + b0.y, 0.f) * w0.y;
    d += fmaxf(di * (a[2] + bfl(hs.y)) + b0.z, 0.f) * w0.z;
    d += fmaxf(di * (a[3] + bfh(hs.y)) + b0.w, 0.f) * w0.w;
    d += fmaxf(di * (a[4] + bfl(hs.z)) + b1.x, 0.f) * w1.x;
    d += fmaxf(di * (a[5] + bfh(hs.z)) + b1.y, 0.f) * w1.y;
    d += fmaxf(di * (a[6] + bfl(hs.w)) + b1.z, 0.f) * w1.z;
    d += fmaxf(di * (a[7] + bfh(hs.w)) + b1.w, 0.f) * w1.w;
#pragma unroll
    for (int m = 1; m <= 4; m <<= 1) d += __shfl_xor(d, m);
    if (valid && f == 0) pdot[node] = d;
}

// ---------------- final: per-graph mean of pdot + bias ----------------
__global__ __launch_bounds__(64) void final_out(const float* __restrict__ pdot,
                                                const int* __restrict__ batch,
                                                const float* __restrict__ bl,
                                                float* __restrict__ out) {
    int g = blockIdx.x;
    __shared__ int slo, shi;
    int lane = threadIdx.x;
    if (lane == 0) {
        int a = 0, b = N_NODES;
        while (a < b) { int m = (a + b) >> 1; if (batch[m] < g) a = m + 1; else b = m; }
        slo = a;
        b = N_NODES;
        while (a < b) { int m = (a + b) >> 1; if (batch[m] < g + 1) a = m + 1; else b = m; }
        shi = a;
    }
    __syncthreads();
    int lo = slo, hi = shi;
    float acc = 0.f;
    for (int i = lo + lane; i < hi; i += 64) acc += pdot[i];
#pragma unroll
    for (int off = 32; off > 0; off >>= 1) acc += __shfl_down(acc, off);
    if (lane == 0) {
        float cnt = (float)(hi - lo);
        out[g] = acc / fmaxf(cnt, 1.0f) + bl[0];
    }
}

extern "C" void kernel_launch(void* const* d_in, const int* in_sizes, int n_in,
                              void* d_out, int out_size, void* d_ws, size_t ws_size,
                              hipStream_t stream) {
    const float* x     = (const float*)d_in[0];
    const int*   src   = (const int*)d_in[1];
    const int*   dst   = (const int*)d_in[2];
    const int*   batch = (const int*)d_in[3];
    const float* W1 = (const float*)d_in[4];  const float* b1 = (const float*)d_in[5];
    const float* W2 = (const float*)d_in[6];  const float* b2 = (const float*)d_in[7];
    const float* W3 = (const float*)d_in[8];  const float* b3 = (const float*)d_in[9];
    const float* Wl = (const float*)d_in[10]; const float* bl = (const float*)d_in[11];
    float* out = (float*)d_out;

    char* ws = (char*)d_ws;
    unsigned short* Abf = (unsigned short*)ws;                       // (N+1)*F bf16 (Hn buf A + zero row)
    unsigned short* Bbf = Abf + (size_t)(N_NODES + 1) * F;           // (N+1)*F bf16 (Hn buf B + zero row)
    float* dinv    = (float*)(Bbf + (size_t)(N_NODES + 1) * F);      // N
    float* pdot    = dinv + N_NODES;                                 // N
    int*   rbeg    = (int*)(pdot + N_NODES);                         // N
    int*   rend    = rbeg + N_NODES;                                 // N
    int*   ord     = rend + N_NODES;                                 // NSLOT
    int*   bcur    = ord + NSLOT;                                    // NBUCK
    unsigned int* bpair = (unsigned int*)(bcur + NBUCK);             // NBUCK*CAP
    int*   eidx    = (int*)(bpair + (size_t)NBUCK * CAP);            // NBUCK*CAP

    const int GEMM_GRID   = (N_NODES + 127) / 128;                   // 391
    const int GATHER_GRID = NSLOT / 32;                              // 1568 (8 nodes/wave)

    // ---- preprocessing: padded-CSR build (rbeg/rend, eidx, dinv, ord, zero rows) ----
    hipMemsetAsync(bcur, 0, NBUCK * sizeof(int), stream);
    partition_edges<<<P3_GRID, 256, 0, stream>>>(src, dst, bcur, bpair);
    bucket_sort<<<NBUCK, 256, 0, stream>>>(bpair, bcur, eidx, rbeg, rend, dinv, ord, Abf, Bbf);

    // ---- layer 1 GEMM (f32 input) ----
    gemm64_f32<<<GEMM_GRID, 256, 0, stream>>>(x, W1, dinv, Abf, N_NODES);

    // ---- layer 1 gather fused with layer-2 GEMM: A -> B ----
    gather_gemm<<<GATHER_GRID, 256, 0, stream>>>(ord, rbeg, rend, eidx, dinv, Abf, b1, W2, Bbf);

    // ---- layer 2 gather fused with layer-3 GEMM: B -> A ----
    gather_gemm<<<GATHER_GRID, 256, 0, stream>>>(ord, rbeg, rend, eidx, dinv, Bbf, b2, W3, Abf);

    // ---- layer 3 gather fused with pooling dot: A -> pdot ----
    gather_pool<<<GATHER_GRID, 256, 0, stream>>>(ord, rbeg, rend, eidx, dinv, Abf, b3, Wl, pdot);

    // ---- final: per-graph mean + bias ----
    final_out<<<N_GRAPHS, 64, 0, stream>>>(pdot, batch, bl, out);
}

// Round 4
// 220.071 us; speedup vs baseline: 1.1348x; 1.1348x over previous
//
#include <hip/hip_runtime.h>

#define N_NODES 50000
#define N_EDGES 800000
#define N_GRAPHS 256
#define F 64
#define NBUCK 196          // ceil(50000/256) coarse buckets (dst>>8)
#define CAP 5120           // per-bucket capacity incl. 4-align padding
#define P3_TILE 2048
#define P3_GRID ((N_EDGES + P3_TILE - 1) / P3_TILE)
#define BCAP 6144
#define ZOFF (N_NODES * 128) // byte offset of the zero row in Hn

// ---- bf16 helpers (RTN), all math stays f32 ----
__device__ __forceinline__ unsigned short f2bf(float f) {
    union { float f; unsigned u; } c; c.f = f;
    unsigned u = c.u + 0x7FFFu + ((c.u >> 16) & 1u);
    return (unsigned short)(u >> 16);
}
__device__ __forceinline__ unsigned pack2bf(float lo, float hi) {
    return (unsigned)f2bf(lo) | ((unsigned)f2bf(hi) << 16);
}
__device__ __forceinline__ float bfl(unsigned u) {
    union { unsigned u; float f; } c; c.u = u << 16; return c.f;
}
__device__ __forceinline__ float bfh(unsigned u) {
    union { unsigned u; float f; } c; c.u = u & 0xFFFF0000u; return c.f;
}

// ---- 4-edge-parallel gather over one node's padded run ----
// 32 lanes/node = 4 edge-slots (es) x 8 feature-lanes (f). Lane handles edges
// k = k0, k0+4, ... (k0 = beg+es); eidx descriptor for the next iteration is
// prefetched (depth-2) with a clamped always-valid slot. Caller must reduce
// a[] across es via shfl_xor(8) + shfl_xor(16).
__device__ __forceinline__ void gather_run4(const int* __restrict__ eidx,
                                            const char* __restrict__ Hb,
                                            int k0, int end, int fo, float* a) {
#pragma unroll
    for (int i = 0; i < 8; ++i) a[i] = 0.f;
    int k = k0;
    int kc = (k < end) ? k : 0;
    int off = eidx[kc];
    while (k < end) {
        int k2 = k + 4;
        int k2c = (k2 < end) ? k2 : 0;
        int offn = eidx[k2c];
        uint4 p = *(const uint4*)(Hb + off + fo);
        a[0] += bfl(p.x); a[1] += bfh(p.x);
        a[2] += bfl(p.y); a[3] += bfh(p.y);
        a[4] += bfl(p.z); a[5] += bfh(p.z);
        a[6] += bfl(p.w); a[7] += bfh(p.w);
        off = offn; k = k2;
    }
}

// ---------------- P1: partition edges into fixed-capacity buckets ----------------
__global__ __launch_bounds__(256) void partition_edges(const int* __restrict__ src,
                                                       const int* __restrict__ dst,
                                                       int* __restrict__ bcur,
                                                       unsigned int* __restrict__ bpair) {
    __shared__ int bh[NBUCK], bloc[NBUCK], bpos[NBUCK];
    int t = threadIdx.x;
    int lo = blockIdx.x * P3_TILE;
    int hi = min(lo + P3_TILE, N_EDGES);
    for (int i = t; i < NBUCK; i += 256) { bh[i] = 0; bpos[i] = 0; }
    __syncthreads();
    for (int e = lo + t; e < hi; e += 256) atomicAdd(&bh[dst[e] >> 8], 1);
    __syncthreads();
    for (int i = t; i < NBUCK; i += 256)
        bloc[i] = bh[i] ? atomicAdd(&bcur[i], bh[i]) : 0;
    __syncthreads();
    for (int e = lo + t; e < hi; e += 256) {
        int d = dst[e];
        int b = d >> 8;
        int r = atomicAdd(&bpos[b], 1);
        bpair[(size_t)b * CAP + bloc[b] + r] = ((unsigned)src[e] << 8) | (unsigned)(d & 255);
    }
}

// ---------------- P2: per-bucket counting sort -> 4-aligned padded CSR ----------------
// (round-2 version: consecutive node ids, no degree permutation)
__global__ __launch_bounds__(256) void bucket_sort(const unsigned int* __restrict__ bpair,
                                                   const int* __restrict__ bcur,
                                                   int* __restrict__ eidx,
                                                   int* __restrict__ rbeg,
                                                   int* __restrict__ rend,
                                                   float* __restrict__ dinv,
                                                   unsigned short* __restrict__ Abf,
                                                   unsigned short* __restrict__ Bbf) {
    __shared__ int cnt[256], s[256], pos[256];
    __shared__ int lout[BCAP];
    int b = blockIdx.x, t = threadIdx.x;
    int base = b * CAP;
    int sz = bcur[b];

    if (b == 0 && t < 8) {
        ((uint4*)Abf)[(size_t)N_NODES * 8 + t] = make_uint4(0u, 0u, 0u, 0u);
        ((uint4*)Bbf)[(size_t)N_NODES * 8 + t] = make_uint4(0u, 0u, 0u, 0u);
    }

    cnt[t] = 0;
    __syncthreads();
    for (int i = t; i < sz; i += 256) atomicAdd(&cnt[bpair[base + i] & 255], 1);
    __syncthreads();
    int v = cnt[t];
    int pv = (v + 3) & ~3;          // padded to multiple of 4
    s[t] = pv;
    __syncthreads();
    for (int off = 1; off < 256; off <<= 1) {
        int u = (t >= off) ? s[t - off] : 0;
        __syncthreads();
        s[t] += u;
        __syncthreads();
    }
    int excl = s[t] - pv;            // padded exclusive prefix
    pos[t] = excl;
    int node = b * 256 + t;
    if (node < N_NODES) {
        rbeg[node] = base + excl;
        rend[node] = base + excl + pv;                 // padded end (loop bound)
        dinv[node] = 1.0f / sqrtf((float)v + 1.0f);    // actual degree +1 self-loop
    }
    int padtot = s[255];             // total padded size of this bucket
    __syncthreads();

    // scatter actual edges
    for (int i = t; i < sz; i += 256) {
        unsigned p = bpair[base + i];
        int r = atomicAdd(&pos[p & 255], 1);
        lout[r] = (int)((p >> 8) << 7);   // src byte offset (src*128, bf16 row)
    }
    __syncthreads();
    // fill pad slots with zero-row sentinel (each thread pads its own node run)
    for (int j = v; j < pv; j++) lout[excl + j] = ZOFF;
    __syncthreads();
    for (int i = t; i < padtot; i += 256) eidx[base + i] = lout[i];
}

// ---------------- GEMM + dinv fold: Hn[i,:] = bf16( (X[i,:] @ W) * dinv[i] ) ----------------
#define XSTRIDE 17
__global__ __launch_bounds__(256) void gemm64_f32(const float* __restrict__ X,
                                                  const float* __restrict__ W,
                                                  const float* __restrict__ dinv,
                                                  unsigned short* __restrict__ Hn, int n) {
    __shared__ float4 sW[64 * 16];
    __shared__ float4 sX[128 * XSTRIDE];
    int tid = threadIdx.x;
    int base = blockIdx.x * 128;

    const float4* W4 = (const float4*)W;
    for (int i = tid; i < 64 * 16; i += 256) sW[i] = W4[i];
    {
        const float4* X4 = (const float4*)X;
        for (int i = tid; i < 128 * 16; i += 256) {
            int r = i >> 4, kg = i & 15;
            int node = base + r;
            sX[r * XSTRIDE + kg] = (node < n) ? X4[(size_t)node * 16 + kg]
                                              : make_float4(0.f, 0.f, 0.f, 0.f);
        }
    }
    __syncthreads();

    int fg = tid & 15;
    int ng = tid >> 4;
    float4 acc[8];
#pragma unroll
    for (int ii = 0; ii < 8; ii++) acc[ii] = make_float4(0.f, 0.f, 0.f, 0.f);

    for (int kg = 0; kg < 16; kg++) {
        float4 xv[8];
#pragma unroll
        for (int ii = 0; ii < 8; ii++) xv[ii] = sX[(ng + 16 * ii) * XSTRIDE + kg];
#pragma unroll
        for (int kk = 0; kk < 4; kk++) {
            float4 wv = sW[(4 * kg + kk) * 16 + fg];
#pragma unroll
            for (int ii = 0; ii < 8; ii++) {
                float xs = (kk == 0) ? xv[ii].x : (kk == 1) ? xv[ii].y
                         : (kk == 2) ? xv[ii].z : xv[ii].w;
                acc[ii].x += wv.x * xs;
                acc[ii].y += wv.y * xs;
                acc[ii].z += wv.z * xs;
                acc[ii].w += wv.w * xs;
            }
        }
    }

    ushort4* H4 = (ushort4*)Hn;
#pragma unroll
    for (int ii = 0; ii < 8; ii++) {
        int node = base + ng + 16 * ii;
        if (node < n) {
            float d = dinv[node];
            float4 o = acc[ii];
            ushort4 u;
            u.x = f2bf(o.x * d); u.y = f2bf(o.y * d);
            u.z = f2bf(o.z * d); u.w = f2bf(o.w * d);
            H4[(size_t)node * 16 + fg] = u;
        }
    }
}

// ---------------- fused gather + next-layer GEMM (layers 1->2, 2->3) ----------------
// 2 nodes/wave, 32 lanes/node (4 edge-slots x 8 feature-lanes) -> 25000 waves
// (vs 1568 before): occupancy becomes resource-limited, not grid-limited.
// Matmul: zero-redundancy K-split (16 lanes K<32, 16 lanes K>=32, shfl_xor(16)
// fold), h broadcast as packed bf16 pairs via ds_bpermute, W transposed in LDS
// so each lane reads its 4 output columns as one float4 per K.
__global__ __launch_bounds__(256) void gather_gemm(const int* __restrict__ rbeg,
                                                   const int* __restrict__ rend,
                                                   const int* __restrict__ eidx,
                                                   const float* __restrict__ dinv,
                                                   const unsigned short* __restrict__ Hin,
                                                   const float* __restrict__ bias,
                                                   const float* __restrict__ W,
                                                   unsigned short* __restrict__ Hout) {
    __shared__ float4 sWt[16 * 65];       // sWt[c4*65+k] = W[k][4c4..4c4+3], padded
    {
        const float4* W4 = (const float4*)W;
        for (int i = threadIdx.x; i < 1024; i += 256) {
            float4 w = W4[i];
            sWt[(i & 15) * 65 + (i >> 4)] = w;
        }
    }
    __syncthreads();

    int wv = (blockIdx.x * blockDim.x + threadIdx.x) >> 6;
    int lane = threadIdx.x & 63;
    int half = lane >> 5;            // which of the 2 nodes
    int sub = lane & 31;
    int es = sub >> 3;               // edge slot 0..3
    int f = sub & 7;                 // feature chunk (8 bf16 = 16B)
    int node = wv * 2 + half;        // N_NODES % (2*4 waves) == 0: always valid
    int beg = rbeg[node];
    int end = rend[node];
    const char* Hb = (const char*)Hin;

    // independent epilogue loads hoisted above the loop
    float di = dinv[node];
    uint4 hs = *(const uint4*)(Hb + (size_t)node * 128 + f * 16);
    float4 bb0 = ((const float4*)bias)[2 * f];
    float4 bb1 = ((const float4*)bias)[2 * f + 1];

    float a[8];
    gather_run4(eidx, Hb, beg + es, end, f * 16, a);

    // fold the 4 edge-slots
#pragma unroll
    for (int i = 0; i < 8; ++i) {
        a[i] += __shfl_xor(a[i], 8);
        a[i] += __shfl_xor(a[i], 16);
    }

    // h for this node's feature chunk f (replicated across es), packed to bf16
    float v0 = fmaxf(di * (a[0] + bfl(hs.x)) + bb0.x, 0.f);
    float v1 = fmaxf(di * (a[1] + bfh(hs.x)) + bb0.y, 0.f);
    float v2 = fmaxf(di * (a[2] + bfl(hs.y)) + bb0.z, 0.f);
    float v3 = fmaxf(di * (a[3] + bfh(hs.y)) + bb0.w, 0.f);
    float v4 = fmaxf(di * (a[4] + bfl(hs.z)) + bb1.x, 0.f);
    float v5 = fmaxf(di * (a[5] + bfh(hs.z)) + bb1.y, 0.f);
    float v6 = fmaxf(di * (a[6] + bfl(hs.w)) + bb1.z, 0.f);
    float v7 = fmaxf(di * (a[7] + bfh(hs.w)) + bb1.w, 0.f);
    unsigned pk0 = pack2bf(v0, v1);
    unsigned pk1 = pack2bf(v2, v3);
    unsigned pk2 = pack2bf(v4, v5);
    unsigned pk3 = pack2bf(v6, v7);

    // y[4c4..4c4+3] over K-half [(sub&16)*2, +32); h[8c+2t(+1)] from lane half*32+c
    int c4 = sub & 15;
    int c0 = (sub & 16) >> 2;        // 0 or 4 (chunk index of K-half start)
    int nb = (lane & 32) << 2;       // bpermute byte base of this node's lanes
    float y0 = 0.f, y1 = 0.f, y2 = 0.f, y3 = 0.f;
#pragma unroll
    for (int cc = 0; cc < 4; ++cc) {
        int c = c0 + cc;
        int ad = nb + 4 * c;
#pragma unroll
        for (int t = 0; t < 4; ++t) {
            unsigned pkt = (t == 0) ? pk0 : (t == 1) ? pk1 : (t == 2) ? pk2 : pk3;
            unsigned u = (unsigned)__builtin_amdgcn_ds_bpermute(ad, (int)pkt);
            float h0 = bfl(u), h1 = bfh(u);
            int k = 8 * c + 2 * t;
            float4 wA = sWt[c4 * 65 + k];
            float4 wB = sWt[c4 * 65 + k + 1];
            y0 += h0 * wA.x + h1 * wB.x;
            y1 += h0 * wA.y + h1 * wB.y;
            y2 += h0 * wA.z + h1 * wB.z;
            y3 += h0 * wA.w + h1 * wB.w;
        }
    }
    // fold the two K-halves
    y0 += __shfl_xor(y0, 16);
    y1 += __shfl_xor(y1, 16);
    y2 += __shfl_xor(y2, 16);
    y3 += __shfl_xor(y3, 16);

    if (sub < 16) {
        uint2 o;
        o.x = pack2bf(y0 * di, y1 * di);
        o.y = pack2bf(y2 * di, y3 * di);
        ((uint2*)Hout)[(size_t)node * 16 + c4] = o;
    }
}

// ---------------- layer-3 gather fused with pooling dot: writes pdot[node] ----------------
__global__ __launch_bounds__(256) void gather_pool(const int* __restrict__ rbeg,
                                                   const int* __restrict__ rend,
                                                   const int* __restrict__ eidx,
                                                   const float* __restrict__ dinv,
                                                   const unsigned short* __restrict__ Hn,
                                                   const float* __restrict__ b,
                                                   const float* __restrict__ Wl,
                                                   float* __restrict__ pdot) {
    int wv = (blockIdx.x * blockDim.x + threadIdx.x) >> 6;
    int lane = threadIdx.x & 63;
    int half = lane >> 5;
    int sub = lane & 31;
    int es = sub >> 3;
    int f = sub & 7;
    int node = wv * 2 + half;
    int beg = rbeg[node];
    int end = rend[node];
    const char* Hb = (const char*)Hn;

    float di = dinv[node];
    uint4 hs = *(const uint4*)(Hb + (size_t)node * 128 + f * 16);
    float4 b0 = ((const float4*)b)[2 * f];
    float4 b1 = ((const float4*)b)[2 * f + 1];
    float4 w0 = ((const float4*)Wl)[2 * f];
    float4 w1 = ((const float4*)Wl)[2 * f + 1];

    float a[8];
    gather_run4(eidx, Hb, beg + es, end, f * 16, a);

#pragma unroll
    for (int i = 0; i < 8; ++i) {
        a[i] += __shfl_xor(a[i], 8);
        a[i] += __shfl_xor(a[i], 16);
    }

    float d = 0.f;
    d += fmaxf(di * (a[0] + bfl(hs.x)) + b0.x, 0.f) * w0.x;
    d += fmaxf(di * (a[1] + bfh(hs.x)) + b0.y, 0.f) * w0.y;
    d += fmaxf(di * (a[2] + bfl(hs.y)) + b0.z, 0.f) * w0.z;
    d += fmaxf(di * (a[3] + bfh(hs.y)) + b0.w, 0.f) * w0.w;
    d += fmaxf(di * (a[4] + bfl(hs.z)) + b1.x, 0.f) * w1.x;
    d += fmaxf(di * (a[5] + bfh(hs.z)) + b1.y, 0.f) * w1.y;
    d += fmaxf(di * (a[6] + bfl(hs.w)) + b1.z, 0.f) * w1.z;
    d += fmaxf(di * (a[7] + bfh(hs.w)) + b1.w, 0.f) * w1.w;
#pragma unroll
    for (int m = 1; m <= 4; m <<= 1) d += __shfl_xor(d, m);
    if (sub == 0) pdot[node] = d;
}

// ---------------- final: per-graph mean of pdot + bias ----------------
__global__ __launch_bounds__(64) void final_out(const float* __restrict__ pdot,
                                                const int* __restrict__ batch,
                                                const float* __restrict__ bl,
                                                float* __restrict__ out) {
    int g = blockIdx.x;
    __shared__ int slo, shi;
    int lane = threadIdx.x;
    if (lane == 0) {
        int a = 0, b = N_NODES;
        while (a < b) { int m = (a + b) >> 1; if (batch[m] < g) a = m + 1; else b = m; }
        slo = a;
        b = N_NODES;
        while (a < b) { int m = (a + b) >> 1; if (batch[m] < g + 1) a = m + 1; else b = m; }
        shi = a;
    }
    __syncthreads();
    int lo = slo, hi = shi;
    float acc = 0.f;
    for (int i = lo + lane; i < hi; i += 64) acc += pdot[i];
#pragma unroll
    for (int off = 32; off > 0; off >>= 1) acc += __shfl_down(acc, off);
    if (lane == 0) {
        float cnt = (float)(hi - lo);
        out[g] = acc / fmaxf(cnt, 1.0f) + bl[0];
    }
}

extern "C" void kernel_launch(void* const* d_in, const int* in_sizes, int n_in,
                              void* d_out, int out_size, void* d_ws, size_t ws_size,
                              hipStream_t stream) {
    const float* x     = (const float*)d_in[0];
    const int*   src   = (const int*)d_in[1];
    const int*   dst   = (const int*)d_in[2];
    const int*   batch = (const int*)d_in[3];
    const float* W1 = (const float*)d_in[4];  const float* b1 = (const float*)d_in[5];
    const float* W2 = (const float*)d_in[6];  const float* b2 = (const float*)d_in[7];
    const float* W3 = (const float*)d_in[8];  const float* b3 = (const float*)d_in[9];
    const float* Wl = (const float*)d_in[10]; const float* bl = (const float*)d_in[11];
    float* out = (float*)d_out;

    char* ws = (char*)d_ws;
    unsigned short* Abf = (unsigned short*)ws;                       // (N+1)*F bf16 (Hn buf A + zero row)
    unsigned short* Bbf = Abf + (size_t)(N_NODES + 1) * F;           // (N+1)*F bf16 (Hn buf B + zero row)
    float* dinv    = (float*)(Bbf + (size_t)(N_NODES + 1) * F);      // N
    float* pdot    = dinv + N_NODES;                                 // N
    int*   rbeg    = (int*)(pdot + N_NODES);                         // N
    int*   rend    = rbeg + N_NODES;                                 // N
    int*   bcur    = rend + N_NODES;                                 // NBUCK
    unsigned int* bpair = (unsigned int*)(bcur + NBUCK);             // NBUCK*CAP
    int*   eidx    = (int*)(bpair + (size_t)NBUCK * CAP);            // NBUCK*CAP

    const int GEMM_GRID   = (N_NODES + 127) / 128;                   // 391
    const int GATHER_GRID = N_NODES / 8;                             // 6250 (2 nodes/wave)

    // ---- preprocessing: padded-CSR build (rbeg/rend, eidx, dinv, zero rows) ----
    hipMemsetAsync(bcur, 0, NBUCK * sizeof(int), stream);
    partition_edges<<<P3_GRID, 256, 0, stream>>>(src, dst, bcur, bpair);
    bucket_sort<<<NBUCK, 256, 0, stream>>>(bpair, bcur, eidx, rbeg, rend, dinv, Abf, Bbf);

    // ---- layer 1 GEMM (f32 input) ----
    gemm64_f32<<<GEMM_GRID, 256, 0, stream>>>(x, W1, dinv, Abf, N_NODES);

    // ---- layer 1 gather fused with layer-2 GEMM: A -> B ----
    gather_gemm<<<GATHER_GRID, 256, 0, stream>>>(rbeg, rend, eidx, dinv, Abf, b1, W2, Bbf);

    // ---- layer 2 gather fused with layer-3 GEMM: B -> A ----
    gather_gemm<<<GATHER_GRID, 256, 0, stream>>>(rbeg, rend, eidx, dinv, Bbf, b2, W3, Abf);

    // ---- layer 3 gather fused with pooling dot: A -> pdot ----
    gather_pool<<<GATHER_GRID, 256, 0, stream>>>(rbeg, rend, eidx, dinv, Abf, b3, Wl, pdot);

    // ---- final: per-graph mean + bias ----
    final_out<<<N_GRAPHS, 64, 0, stream>>>(pdot, batch, bl, out);
}

// Round 5
// 216.172 us; speedup vs baseline: 1.1552x; 1.0180x over previous
//
#include <hip/hip_runtime.h>

#define N_NODES 50000
#define N_EDGES 800000
#define N_GRAPHS 256
#define F 64
#define NBUCK 196          // ceil(50000/256) coarse buckets (dst>>8)
#define CAP 5120           // per-bucket capacity incl. 4-align padding
#define P3_TILE 2048
#define P3_GRID ((N_EDGES + P3_TILE - 1) / P3_TILE)
#define BCAP 6144
#define ZOFF (N_NODES * 64)   // byte offset of the zero row in a 64B-stride half-table
#define NSUB 1563             // ceil(50000/32) node-groups of 32
#define GATHER_GRID (391 * 8) // 3128: 8 XCD-slots x 391 q-steps covers 2 halves x NSUB

// ---- bf16 helpers (RTN), all math stays f32 ----
__device__ __forceinline__ unsigned short f2bf(float f) {
    union { float f; unsigned u; } c; c.f = f;
    unsigned u = c.u + 0x7FFFu + ((c.u >> 16) & 1u);
    return (unsigned short)(u >> 16);
}
__device__ __forceinline__ unsigned pack2bf(float lo, float hi) {
    return (unsigned)f2bf(lo) | ((unsigned)f2bf(hi) << 16);
}
__device__ __forceinline__ float bfl(unsigned u) {
    union { unsigned u; float f; } c; c.u = u << 16; return c.f;
}
__device__ __forceinline__ float bfh(unsigned u) {
    union { unsigned u; float f; } c; c.u = u & 0xFFFF0000u; return c.f;
}

// ---- depth-2 software-pipelined gather over one node's padded run (64B half-rows) ----
__device__ __forceinline__ void gather_run_h(const int* __restrict__ eidx,
                                             const char* __restrict__ Hb,
                                             int beg, int end, int fo, float* a) {
    a[0] = a[1] = a[2] = a[3] = 0.f;
    int kb = (beg < end) ? beg : 0;          // always-valid descriptor slot
    int4 oc = *(const int4*)(eidx + kb);
    int k1 = beg + 4;
    int k1c = (k1 < end) ? k1 : kb;
    int4 on = *(const int4*)(eidx + k1c);
    uint2 pc = *(const uint2*)(Hb + oc.x + fo);
    uint2 qc = *(const uint2*)(Hb + oc.y + fo);
    uint2 rc = *(const uint2*)(Hb + oc.z + fo);
    uint2 wc = *(const uint2*)(Hb + oc.w + fo);
    for (int k = beg; k < end; k += 4) {
        int k2 = k + 8;
        int k2c = (k2 < end) ? k2 : kb;
        int4 of = *(const int4*)(eidx + k2c);
        uint2 pn = *(const uint2*)(Hb + on.x + fo);
        uint2 qn = *(const uint2*)(Hb + on.y + fo);
        uint2 rn = *(const uint2*)(Hb + on.z + fo);
        uint2 wn = *(const uint2*)(Hb + on.w + fo);
        a[0] += (bfl(pc.x) + bfl(qc.x)) + (bfl(rc.x) + bfl(wc.x));
        a[1] += (bfh(pc.x) + bfh(qc.x)) + (bfh(rc.x) + bfh(wc.x));
        a[2] += (bfl(pc.y) + bfl(qc.y)) + (bfl(rc.y) + bfl(wc.y));
        a[3] += (bfh(pc.y) + bfh(qc.y)) + (bfh(rc.y) + bfh(wc.y));
        oc = on; on = of;
        pc = pn; qc = qn; rc = rn; wc = wn;
    }
}

// ---------------- P1: partition edges into fixed-capacity buckets ----------------
__global__ __launch_bounds__(256) void partition_edges(const int* __restrict__ src,
                                                       const int* __restrict__ dst,
                                                       int* __restrict__ bcur,
                                                       unsigned int* __restrict__ bpair) {
    __shared__ int bh[NBUCK], bloc[NBUCK], bpos[NBUCK];
    int t = threadIdx.x;
    int lo = blockIdx.x * P3_TILE;
    int hi = min(lo + P3_TILE, N_EDGES);
    for (int i = t; i < NBUCK; i += 256) { bh[i] = 0; bpos[i] = 0; }
    __syncthreads();
    for (int e = lo + t; e < hi; e += 256) atomicAdd(&bh[dst[e] >> 8], 1);
    __syncthreads();
    for (int i = t; i < NBUCK; i += 256)
        bloc[i] = bh[i] ? atomicAdd(&bcur[i], bh[i]) : 0;
    __syncthreads();
    for (int e = lo + t; e < hi; e += 256) {
        int d = dst[e];
        int b = d >> 8;
        int r = atomicAdd(&bpos[b], 1);
        bpair[(size_t)b * CAP + bloc[b] + r] = ((unsigned)src[e] << 8) | (unsigned)(d & 255);
    }
}

// ---------------- P2: per-bucket counting sort -> 4-aligned padded CSR ----------------
// eidx entries are src*64 (byte offset into the 64B-stride half-tables).
// Zeroes the zero row (row N) of BOTH scaled half-tables SA/SB.
__global__ __launch_bounds__(256) void bucket_sort(const unsigned int* __restrict__ bpair,
                                                   const int* __restrict__ bcur,
                                                   int* __restrict__ eidx,
                                                   int* __restrict__ rbeg,
                                                   int* __restrict__ rend,
                                                   float* __restrict__ dinv,
                                                   unsigned short* __restrict__ SA,
                                                   unsigned short* __restrict__ SB) {
    __shared__ int cnt[256], s[256], pos[256];
    __shared__ int lout[BCAP];
    int b = blockIdx.x, t = threadIdx.x;
    int base = b * CAP;
    int sz = bcur[b];

    if (b == 0 && t < 4) {
        ((uint4*)SA)[(size_t)N_NODES * 4 + t] = make_uint4(0u, 0u, 0u, 0u);
        ((uint4*)SB)[(size_t)N_NODES * 4 + t] = make_uint4(0u, 0u, 0u, 0u);
    }

    cnt[t] = 0;
    __syncthreads();
    for (int i = t; i < sz; i += 256) atomicAdd(&cnt[bpair[base + i] & 255], 1);
    __syncthreads();
    int v = cnt[t];
    int pv = (v + 3) & ~3;          // padded to multiple of 4
    s[t] = pv;
    __syncthreads();
    for (int off = 1; off < 256; off <<= 1) {
        int u = (t >= off) ? s[t - off] : 0;
        __syncthreads();
        s[t] += u;
        __syncthreads();
    }
    int excl = s[t] - pv;            // padded exclusive prefix
    pos[t] = excl;
    int node = b * 256 + t;
    if (node < N_NODES) {
        rbeg[node] = base + excl;
        rend[node] = base + excl + pv;                 // padded end (loop bound)
        dinv[node] = 1.0f / sqrtf((float)v + 1.0f);    // actual degree +1 self-loop
    }
    int padtot = s[255];             // total padded size of this bucket
    __syncthreads();

    // scatter actual edges
    for (int i = t; i < sz; i += 256) {
        unsigned p = bpair[base + i];
        int r = atomicAdd(&pos[p & 255], 1);
        lout[r] = (int)((p >> 8) << 6);   // src byte offset (src*64, bf16 half-row)
    }
    __syncthreads();
    // fill pad slots with zero-row sentinel
    for (int j = v; j < pv; j++) lout[excl + j] = ZOFF;
    __syncthreads();
    for (int i = t; i < padtot; i += 256) eidx[base + i] = lout[i];
}

// ---------------- GEMM + dinv fold: S[i,:] = bf16( (X[i,:] @ W) * dinv[i] ) ----------------
// Writes feature halves to separate tables SA (feats 0-31) and SB (32-63).
#define XSTRIDE 17
template <bool BF16IN>
__global__ __launch_bounds__(256) void gemm64_t(const void* __restrict__ Xa,
                                                const void* __restrict__ Xb,
                                                const float* __restrict__ W,
                                                const float* __restrict__ dinv,
                                                unsigned short* __restrict__ SA,
                                                unsigned short* __restrict__ SB, int n) {
    __shared__ float4 sW[64 * 16];
    __shared__ float4 sX[128 * XSTRIDE];
    int tid = threadIdx.x;
    int base = blockIdx.x * 128;

    const float4* W4 = (const float4*)W;
    for (int i = tid; i < 64 * 16; i += 256) sW[i] = W4[i];
    if (BF16IN) {
        const uint4* A4 = (const uint4*)Xa;   // half rows: 4 uint4 (32 bf16)
        const uint4* B4 = (const uint4*)Xb;
        for (int i = tid; i < 128 * 8; i += 256) {
            int r = i >> 3, c = i & 7;
            int node = base + r;
            uint4 u = make_uint4(0u, 0u, 0u, 0u);
            if (node < n) u = (c < 4) ? A4[(size_t)node * 4 + c]
                                      : B4[(size_t)node * 4 + (c - 4)];
            sX[r * XSTRIDE + 2 * c]     = make_float4(bfl(u.x), bfh(u.x), bfl(u.y), bfh(u.y));
            sX[r * XSTRIDE + 2 * c + 1] = make_float4(bfl(u.z), bfh(u.z), bfl(u.w), bfh(u.w));
        }
    } else {
        const float4* X4 = (const float4*)Xa;
        for (int i = tid; i < 128 * 16; i += 256) {
            int r = i >> 4, kg = i & 15;
            int node = base + r;
            sX[r * XSTRIDE + kg] = (node < n) ? X4[(size_t)node * 16 + kg]
                                              : make_float4(0.f, 0.f, 0.f, 0.f);
        }
    }
    __syncthreads();

    int fg = tid & 15;
    int ng = tid >> 4;
    float4 acc[8];
#pragma unroll
    for (int ii = 0; ii < 8; ii++) acc[ii] = make_float4(0.f, 0.f, 0.f, 0.f);

    for (int kg = 0; kg < 16; kg++) {
        float4 xv[8];
#pragma unroll
        for (int ii = 0; ii < 8; ii++) xv[ii] = sX[(ng + 16 * ii) * XSTRIDE + kg];
#pragma unroll
        for (int kk = 0; kk < 4; kk++) {
            float4 wv = sW[(4 * kg + kk) * 16 + fg];
#pragma unroll
            for (int ii = 0; ii < 8; ii++) {
                float xs = (kk == 0) ? xv[ii].x : (kk == 1) ? xv[ii].y
                         : (kk == 2) ? xv[ii].z : xv[ii].w;
                acc[ii].x += wv.x * xs;
                acc[ii].y += wv.y * xs;
                acc[ii].z += wv.z * xs;
                acc[ii].w += wv.w * xs;
            }
        }
    }

#pragma unroll
    for (int ii = 0; ii < 8; ii++) {
        int node = base + ng + 16 * ii;
        if (node < n) {
            float d = dinv[node];
            float4 o = acc[ii];
            ushort4 u;
            u.x = f2bf(o.x * d); u.y = f2bf(o.y * d);
            u.z = f2bf(o.z * d); u.w = f2bf(o.w * d);
            if (fg < 8) ((ushort4*)SA)[(size_t)node * 8 + fg] = u;
            else        ((ushort4*)SB)[(size_t)node * 8 + (fg - 8)] = u;
        }
    }
}

// ---------------- half-feature gather (layers 1,2): h_half = relu(di*(agg+self)+b) ----------------
// XCD-pinned halves: blockIdx%8 in {0..3} -> half A (SA, 3.2MB, L2-resident on
// XCDs 0-3); {4..7} -> half B. 8 nodes/wave, 8 lanes/node x 8B of the 64B row.
__global__ __launch_bounds__(256) void gather_half(const int* __restrict__ rbeg,
                                                   const int* __restrict__ rend,
                                                   const int* __restrict__ eidx,
                                                   const float* __restrict__ dinv,
                                                   const unsigned short* __restrict__ SA,
                                                   const unsigned short* __restrict__ SB,
                                                   const float* __restrict__ bias,
                                                   unsigned short* __restrict__ hA,
                                                   unsigned short* __restrict__ hB) {
    int bid = blockIdx.x;
    int xcd = bid & 7;
    int half = xcd >> 2;
    int sub = (bid >> 3) * 4 + (xcd & 3);
    if (sub >= NSUB) return;
    int wid = threadIdx.x >> 6;
    int lane = threadIdx.x & 63;
    int ns = lane >> 3, f = lane & 7;
    int node = sub * 32 + wid * 8 + ns;
    if (node >= N_NODES) return;          // wave-uniform (N % 8 == 0)
    const char* Hb = (const char*)(half ? SB : SA);
    unsigned short* out = half ? hB : hA;

    int beg = rbeg[node];
    int end = rend[node];
    float di = dinv[node];
    uint2 hs = *(const uint2*)(Hb + (size_t)node * 64 + f * 8);
    float4 bb = ((const float4*)bias)[half * 8 + f];

    float a[4];
    gather_run_h(eidx, Hb, beg, end, f * 8, a);

    float v0 = fmaxf(di * (a[0] + bfl(hs.x)) + bb.x, 0.f);
    float v1 = fmaxf(di * (a[1] + bfh(hs.x)) + bb.y, 0.f);
    float v2 = fmaxf(di * (a[2] + bfl(hs.y)) + bb.z, 0.f);
    float v3 = fmaxf(di * (a[3] + bfh(hs.y)) + bb.w, 0.f);
    uint2 o;
    o.x = pack2bf(v0, v1);
    o.y = pack2bf(v2, v3);
    ((uint2*)out)[(size_t)node * 8 + f] = o;
}

// ---------------- layer-3 half gather fused with pooling dot: partial pdot ----------------
__global__ __launch_bounds__(256) void gather_pool_half(const int* __restrict__ rbeg,
                                                        const int* __restrict__ rend,
                                                        const int* __restrict__ eidx,
                                                        const float* __restrict__ dinv,
                                                        const unsigned short* __restrict__ SA,
                                                        const unsigned short* __restrict__ SB,
                                                        const float* __restrict__ bias,
                                                        const float* __restrict__ Wl,
                                                        float* __restrict__ pdotA,
                                                        float* __restrict__ pdotB) {
    int bid = blockIdx.x;
    int xcd = bid & 7;
    int half = xcd >> 2;
    int sub = (bid >> 3) * 4 + (xcd & 3);
    if (sub >= NSUB) return;
    int wid = threadIdx.x >> 6;
    int lane = threadIdx.x & 63;
    int ns = lane >> 3, f = lane & 7;
    int node = sub * 32 + wid * 8 + ns;
    if (node >= N_NODES) return;
    const char* Hb = (const char*)(half ? SB : SA);
    float* pout = half ? pdotB : pdotA;

    int beg = rbeg[node];
    int end = rend[node];
    float di = dinv[node];
    uint2 hs = *(const uint2*)(Hb + (size_t)node * 64 + f * 8);
    float4 bb = ((const float4*)bias)[half * 8 + f];
    float4 wl = ((const float4*)Wl)[half * 8 + f];

    float a[4];
    gather_run_h(eidx, Hb, beg, end, f * 8, a);

    float d = 0.f;
    d += fmaxf(di * (a[0] + bfl(hs.x)) + bb.x, 0.f) * wl.x;
    d += fmaxf(di * (a[1] + bfh(hs.x)) + bb.y, 0.f) * wl.y;
    d += fmaxf(di * (a[2] + bfl(hs.y)) + bb.z, 0.f) * wl.z;
    d += fmaxf(di * (a[3] + bfh(hs.y)) + bb.w, 0.f) * wl.w;
#pragma unroll
    for (int m = 1; m <= 4; m <<= 1) d += __shfl_xor(d, m);
    if (f == 0) pout[node] = d;
}

// ---------------- final: per-graph mean of (pdotA+pdotB) + bias ----------------
__global__ __launch_bounds__(64) void final_out(const float* __restrict__ pdotA,
                                                const float* __restrict__ pdotB,
                                                const int* __restrict__ batch,
                                                const float* __restrict__ bl,
                                                float* __restrict__ out) {
    int g = blockIdx.x;
    __shared__ int slo, shi;
    int lane = threadIdx.x;
    if (lane == 0) {
        int a = 0, b = N_NODES;
        while (a < b) { int m = (a + b) >> 1; if (batch[m] < g) a = m + 1; else b = m; }
        slo = a;
        b = N_NODES;
        while (a < b) { int m = (a + b) >> 1; if (batch[m] < g + 1) a = m + 1; else b = m; }
        shi = a;
    }
    __syncthreads();
    int lo = slo, hi = shi;
    float acc = 0.f;
    for (int i = lo + lane; i < hi; i += 64) acc += pdotA[i] + pdotB[i];
#pragma unroll
    for (int off = 32; off > 0; off >>= 1) acc += __shfl_down(acc, off);
    if (lane == 0) {
        float cnt = (float)(hi - lo);
        out[g] = acc / fmaxf(cnt, 1.0f) + bl[0];
    }
}

extern "C" void kernel_launch(void* const* d_in, const int* in_sizes, int n_in,
                              void* d_out, int out_size, void* d_ws, size_t ws_size,
                              hipStream_t stream) {
    const float* x     = (const float*)d_in[0];
    const int*   src   = (const int*)d_in[1];
    const int*   dst   = (const int*)d_in[2];
    const int*   batch = (const int*)d_in[3];
    const float* W1 = (const float*)d_in[4];  const float* b1 = (const float*)d_in[5];
    const float* W2 = (const float*)d_in[6];  const float* b2 = (const float*)d_in[7];
    const float* W3 = (const float*)d_in[8];  const float* b3 = (const float*)d_in[9];
    const float* Wl = (const float*)d_in[10]; const float* bl = (const float*)d_in[11];
    float* out = (float*)d_out;

    char* ws = (char*)d_ws;
    unsigned short* SA = (unsigned short*)ws;                        // (N+1)*32 bf16 scaled half A
    unsigned short* SB = SA + (size_t)(N_NODES + 1) * 32;            // (N+1)*32 bf16 scaled half B
    unsigned short* hA = SB + (size_t)(N_NODES + 1) * 32;            // N*32 bf16 activation half A
    unsigned short* hB = hA + (size_t)N_NODES * 32;                  // N*32 bf16 activation half B
    float* dinv    = (float*)(hB + (size_t)N_NODES * 32);            // N
    float* pdotA   = dinv + N_NODES;                                 // N
    float* pdotB   = pdotA + N_NODES;                                // N
    int*   rbeg    = (int*)(pdotB + N_NODES);                        // N
    int*   rend    = rbeg + N_NODES;                                 // N
    int*   bcur    = rend + N_NODES;                                 // NBUCK
    unsigned int* bpair = (unsigned int*)(bcur + NBUCK);             // NBUCK*CAP
    int*   eidx    = (int*)(bpair + (size_t)NBUCK * CAP);            // NBUCK*CAP

    const int GEMM_GRID = (N_NODES + 127) / 128;                     // 391

    // ---- preprocessing: padded-CSR build (rbeg/rend, eidx, dinv, zero rows) ----
    hipMemsetAsync(bcur, 0, NBUCK * sizeof(int), stream);
    partition_edges<<<P3_GRID, 256, 0, stream>>>(src, dst, bcur, bpair);
    bucket_sort<<<NBUCK, 256, 0, stream>>>(bpair, bcur, eidx, rbeg, rend, dinv, SA, SB);

    // ---- layer 1 ----
    gemm64_t<false><<<GEMM_GRID, 256, 0, stream>>>((const void*)x, nullptr, W1, dinv, SA, SB, N_NODES);
    gather_half<<<GATHER_GRID, 256, 0, stream>>>(rbeg, rend, eidx, dinv, SA, SB, b1, hA, hB);

    // ---- layer 2 ----
    gemm64_t<true><<<GEMM_GRID, 256, 0, stream>>>((const void*)hA, (const void*)hB, W2, dinv, SA, SB, N_NODES);
    gather_half<<<GATHER_GRID, 256, 0, stream>>>(rbeg, rend, eidx, dinv, SA, SB, b2, hA, hB);

    // ---- layer 3 (gather fused with pooling dot) ----
    gemm64_t<true><<<GEMM_GRID, 256, 0, stream>>>((const void*)hA, (const void*)hB, W3, dinv, SA, SB, N_NODES);
    gather_pool_half<<<GATHER_GRID, 256, 0, stream>>>(rbeg, rend, eidx, dinv, SA, SB, b3, Wl, pdotA, pdotB);

    // ---- final: per-graph mean + bias ----
    final_out<<<N_GRAPHS, 64, 0, stream>>>(pdotA, pdotB, batch, bl, out);
}

// Round 6
// 211.213 us; speedup vs baseline: 1.1823x; 1.0235x over previous
//
#include <hip/hip_runtime.h>

#define N_NODES 50000
#define N_EDGES 800000
#define N_GRAPHS 256
#define F 64
#define NBUCK 196          // ceil(50000/256) coarse buckets (dst>>8)
#define CAP 6656           // per-bucket capacity incl. two-segment 4-align padding
#define P3_TILE 2048
#define P3_GRID ((N_EDGES + P3_TILE - 1) / P3_TILE)
#define BCAP 6656
#define ZOFF (N_NODES * 128)  // byte offset of the zero row in S (row 50000)
#define NSPLIT 25000          // src-half split: <25000 -> low (XCD 0-3), else high
#define NSUB 1563             // ceil(50000/32) node-chunks of 32
#define GATHER_GRID (391 * 8) // 3128 blocks: (xcd&3)-interleaved chunks x 2 halves
#define PDOT_GRID 1563

// ---- bf16 helpers (RTN), all math stays f32 ----
__device__ __forceinline__ unsigned short f2bf(float f) {
    union { float f; unsigned u; } c; c.f = f;
    unsigned u = c.u + 0x7FFFu + ((c.u >> 16) & 1u);
    return (unsigned short)(u >> 16);
}
__device__ __forceinline__ unsigned pack2bf(float lo, float hi) {
    return (unsigned)f2bf(lo) | ((unsigned)f2bf(hi) << 16);
}
__device__ __forceinline__ float bfl(unsigned u) {
    union { unsigned u; float f; } c; c.u = u << 16; return c.f;
}
__device__ __forceinline__ float bfh(unsigned u) {
    union { unsigned u; float f; } c; c.u = u & 0xFFFF0000u; return c.f;
}

// ---- depth-2 software-pipelined gather over one padded edge segment (128B rows) ----
__device__ __forceinline__ void gather_run(const int* __restrict__ eidx,
                                           const char* __restrict__ Hb,
                                           int beg, int end, int fo, float* a) {
#pragma unroll
    for (int i = 0; i < 8; ++i) a[i] = 0.f;
    int kb = (beg < end) ? beg : 0;          // always-valid descriptor slot
    int4 oc = *(const int4*)(eidx + kb);
    int k1 = beg + 4;
    int k1c = (k1 < end) ? k1 : kb;
    int4 on = *(const int4*)(eidx + k1c);
    uint4 pc = *(const uint4*)(Hb + oc.x + fo);
    uint4 qc = *(const uint4*)(Hb + oc.y + fo);
    uint4 rc = *(const uint4*)(Hb + oc.z + fo);
    uint4 wc = *(const uint4*)(Hb + oc.w + fo);
    for (int k = beg; k < end; k += 4) {
        int k2 = k + 8;
        int k2c = (k2 < end) ? k2 : kb;
        int4 of = *(const int4*)(eidx + k2c);
        uint4 pn = *(const uint4*)(Hb + on.x + fo);
        uint4 qn = *(const uint4*)(Hb + on.y + fo);
        uint4 rn = *(const uint4*)(Hb + on.z + fo);
        uint4 wn = *(const uint4*)(Hb + on.w + fo);
        a[0] += (bfl(pc.x) + bfl(qc.x)) + (bfl(rc.x) + bfl(wc.x));
        a[1] += (bfh(pc.x) + bfh(qc.x)) + (bfh(rc.x) + bfh(wc.x));
        a[2] += (bfl(pc.y) + bfl(qc.y)) + (bfl(rc.y) + bfl(wc.y));
        a[3] += (bfh(pc.y) + bfh(qc.y)) + (bfh(rc.y) + bfh(wc.y));
        a[4] += (bfl(pc.z) + bfl(qc.z)) + (bfl(rc.z) + bfl(wc.z));
        a[5] += (bfh(pc.z) + bfh(qc.z)) + (bfh(rc.z) + bfh(wc.z));
        a[6] += (bfl(pc.w) + bfl(qc.w)) + (bfl(rc.w) + bfl(wc.w));
        a[7] += (bfh(pc.w) + bfh(qc.w)) + (bfh(rc.w) + bfh(wc.w));
        oc = on; on = of;
        pc = pn; qc = qn; rc = rn; wc = wn;
    }
}

// ---------------- P1: partition edges into fixed-capacity buckets ----------------
__global__ __launch_bounds__(256) void partition_edges(const int* __restrict__ src,
                                                       const int* __restrict__ dst,
                                                       int* __restrict__ bcur,
                                                       unsigned int* __restrict__ bpair) {
    __shared__ int bh[NBUCK], bloc[NBUCK], bpos[NBUCK];
    int t = threadIdx.x;
    int lo = blockIdx.x * P3_TILE;
    int hi = min(lo + P3_TILE, N_EDGES);
    for (int i = t; i < NBUCK; i += 256) { bh[i] = 0; bpos[i] = 0; }
    __syncthreads();
    for (int e = lo + t; e < hi; e += 256) atomicAdd(&bh[dst[e] >> 8], 1);
    __syncthreads();
    for (int i = t; i < NBUCK; i += 256)
        bloc[i] = bh[i] ? atomicAdd(&bcur[i], bh[i]) : 0;
    __syncthreads();
    for (int e = lo + t; e < hi; e += 256) {
        int d = dst[e];
        int b = d >> 8;
        int r = atomicAdd(&bpos[b], 1);
        bpair[(size_t)b * CAP + bloc[b] + r] = ((unsigned)src[e] << 8) | (unsigned)(d & 255);
    }
}

// ---------------- P2: per-bucket counting sort -> per-node low/high padded segments ----------------
// Each node's run splits into a low-src segment and a high-src segment, each
// 4-aligned and padded with ZOFF zero-row sentinels. Also zeroes the S zero row.
__global__ __launch_bounds__(256) void bucket_sort(const unsigned int* __restrict__ bpair,
                                                   const int* __restrict__ bcur,
                                                   int* __restrict__ eidx,
                                                   int* __restrict__ rbegL,
                                                   int* __restrict__ rendL,
                                                   int* __restrict__ rbegH,
                                                   int* __restrict__ rendH,
                                                   float* __restrict__ dinv,
                                                   unsigned short* __restrict__ S) {
    __shared__ int cntL[256], cntH[256], s[256], posL[256], posH[256];
    __shared__ int lout[BCAP];
    int b = blockIdx.x, t = threadIdx.x;
    int base = b * CAP;
    int sz = bcur[b];

    if (b == 0 && t < 8) ((uint4*)S)[(size_t)N_NODES * 8 + t] = make_uint4(0u, 0u, 0u, 0u);

    cntL[t] = 0; cntH[t] = 0;
    __syncthreads();
    for (int i = t; i < sz; i += 256) {
        unsigned p = bpair[base + i];
        atomicAdd(((p >> 8) < (unsigned)NSPLIT) ? &cntL[p & 255] : &cntH[p & 255], 1);
    }
    __syncthreads();
    int vL = cntL[t], vH = cntH[t];
    int pvL = (vL + 3) & ~3;
    int pvH = (vH + 3) & ~3;
    s[t] = pvL + pvH;
    __syncthreads();
    for (int off = 1; off < 256; off <<= 1) {
        int u = (t >= off) ? s[t - off] : 0;
        __syncthreads();
        s[t] += u;
        __syncthreads();
    }
    int excl = s[t] - (pvL + pvH);
    posL[t] = excl;
    posH[t] = excl + pvL;
    int node = b * 256 + t;
    if (node < N_NODES) {
        rbegL[node] = base + excl;
        rendL[node] = base + excl + pvL;
        rbegH[node] = base + excl + pvL;
        rendH[node] = base + excl + pvL + pvH;
        dinv[node] = 1.0f / sqrtf((float)(vL + vH) + 1.0f);
    }
    int padtot = s[255];
    __syncthreads();

    // scatter actual edges into their node+half segment
    for (int i = t; i < sz; i += 256) {
        unsigned p = bpair[base + i];
        int d = p & 255;
        int r = atomicAdd(((p >> 8) < (unsigned)NSPLIT) ? &posL[d] : &posH[d], 1);
        lout[r] = (int)((p >> 8) << 7);   // src byte offset (src*128)
    }
    __syncthreads();
    // pad both segments with zero-row sentinel
    for (int j = vL; j < pvL; j++) lout[excl + j] = ZOFF;
    for (int j = vH; j < pvH; j++) lout[excl + pvL + j] = ZOFF;
    __syncthreads();
    for (int i = t; i < padtot; i += 256) eidx[base + i] = lout[i];
}

// ---------------- GEMM: S[i,:] = bf16( (h[i,:] @ W) * dinv[i] ) ----------------
// MODE 0: h = X (f32 input, layer 1).
// MODE 1: h = relu(dinv[i]*(aggL[i]+aggH[i]+S[i]) + bias)  (fold of the previous
//         layer's gather partials; removes one bf16 round-trip of h).
#define XSTRIDE 17
template <int MODE>
__global__ __launch_bounds__(256) void gemm64_t(const float* __restrict__ X,
                                                const float* __restrict__ aggL,
                                                const float* __restrict__ aggH,
                                                const unsigned short* __restrict__ Sself,
                                                const float* __restrict__ bias,
                                                const float* __restrict__ W,
                                                const float* __restrict__ dinv,
                                                unsigned short* __restrict__ Sout, int n) {
    __shared__ float4 sW[64 * 16];
    __shared__ float4 sX[128 * XSTRIDE];
    int tid = threadIdx.x;
    int base = blockIdx.x * 128;

    const float4* W4 = (const float4*)W;
    for (int i = tid; i < 64 * 16; i += 256) sW[i] = W4[i];
    if (MODE == 0) {
        const float4* X4 = (const float4*)X;
        for (int i = tid; i < 128 * 16; i += 256) {
            int r = i >> 4, kg = i & 15;
            int node = base + r;
            sX[r * XSTRIDE + kg] = (node < n) ? X4[(size_t)node * 16 + kg]
                                              : make_float4(0.f, 0.f, 0.f, 0.f);
        }
    } else {
        const float4* L4 = (const float4*)aggL;
        const float4* H4 = (const float4*)aggH;
        const uint2* S2 = (const uint2*)Sself;
        for (int i = tid; i < 128 * 16; i += 256) {
            int r = i >> 4, kg = i & 15;
            int node = base + r;
            float4 hv = make_float4(0.f, 0.f, 0.f, 0.f);
            if (node < n) {
                float4 L = L4[(size_t)node * 16 + kg];
                float4 Hh = H4[(size_t)node * 16 + kg];
                uint2 su = S2[(size_t)node * 16 + kg];
                float4 bb = ((const float4*)bias)[kg];
                float di = dinv[node];
                hv.x = fmaxf(di * (L.x + Hh.x + bfl(su.x)) + bb.x, 0.f);
                hv.y = fmaxf(di * (L.y + Hh.y + bfh(su.x)) + bb.y, 0.f);
                hv.z = fmaxf(di * (L.z + Hh.z + bfl(su.y)) + bb.z, 0.f);
                hv.w = fmaxf(di * (L.w + Hh.w + bfh(su.y)) + bb.w, 0.f);
            }
            sX[r * XSTRIDE + kg] = hv;
        }
    }
    __syncthreads();

    int fg = tid & 15;
    int ng = tid >> 4;
    float4 acc[8];
#pragma unroll
    for (int ii = 0; ii < 8; ii++) acc[ii] = make_float4(0.f, 0.f, 0.f, 0.f);

    for (int kg = 0; kg < 16; kg++) {
        float4 xv[8];
#pragma unroll
        for (int ii = 0; ii < 8; ii++) xv[ii] = sX[(ng + 16 * ii) * XSTRIDE + kg];
#pragma unroll
        for (int kk = 0; kk < 4; kk++) {
            float4 wv = sW[(4 * kg + kk) * 16 + fg];
#pragma unroll
            for (int ii = 0; ii < 8; ii++) {
                float xs = (kk == 0) ? xv[ii].x : (kk == 1) ? xv[ii].y
                         : (kk == 2) ? xv[ii].z : xv[ii].w;
                acc[ii].x += wv.x * xs;
                acc[ii].y += wv.y * xs;
                acc[ii].z += wv.z * xs;
                acc[ii].w += wv.w * xs;
            }
        }
    }

    ushort4* O4 = (ushort4*)Sout;
#pragma unroll
    for (int ii = 0; ii < 8; ii++) {
        int node = base + ng + 16 * ii;
        if (node < n) {
            float d = dinv[node];
            float4 o = acc[ii];
            ushort4 u;
            u.x = f2bf(o.x * d); u.y = f2bf(o.y * d);
            u.z = f2bf(o.z * d); u.w = f2bf(o.w * d);
            O4[(size_t)node * 16 + fg] = u;
        }
    }
}

// ---------------- split gather: per (node, half) partial sums -> f32 agg ----------------
// XCD-pinned: blockIdx&7 in {0..3} -> low half (src<25000, 3.2MB of S, resident
// in XCD 0-3 L2); {4..7} -> high half. Line requests stay 1 per edge (full 128B
// rows); all should be ~200cy L2 hits.
__global__ __launch_bounds__(256) void gather_split(const int* __restrict__ rbegL,
                                                    const int* __restrict__ rendL,
                                                    const int* __restrict__ rbegH,
                                                    const int* __restrict__ rendH,
                                                    const int* __restrict__ eidx,
                                                    const unsigned short* __restrict__ S,
                                                    float* __restrict__ aggL,
                                                    float* __restrict__ aggH) {
    int bid = blockIdx.x;
    int xcd = bid & 7;
    int h = xcd >> 2;
    int sub = (bid >> 3) * 4 + (xcd & 3);
    if (sub >= NSUB) return;
    int wid = threadIdx.x >> 6;
    int lane = threadIdx.x & 63;
    int ns = lane >> 3, f = lane & 7;
    int node = sub * 32 + wid * 8 + ns;
    bool valid = node < N_NODES;
    int nodec = valid ? node : 0;
    const int* rb = h ? rbegH : rbegL;
    const int* re = h ? rendH : rendL;
    int beg = valid ? rb[nodec] : 0;
    int end = valid ? re[nodec] : 0;

    float a[8];
    gather_run(eidx, (const char*)S, beg, end, f * 16, a);

    if (valid) {
        float* agg = h ? aggH : aggL;
        float4* o = (float4*)(agg + (size_t)node * 64 + f * 8);
        o[0] = make_float4(a[0], a[1], a[2], a[3]);
        o[1] = make_float4(a[4], a[5], a[6], a[7]);
    }
}

// ---------------- layer-3 finalize + pooling dot: pdot[node] ----------------
__global__ __launch_bounds__(256) void pdot_kernel(const float* __restrict__ aggL,
                                                   const float* __restrict__ aggH,
                                                   const unsigned short* __restrict__ S,
                                                   const float* __restrict__ dinv,
                                                   const float* __restrict__ b3,
                                                   const float* __restrict__ Wl,
                                                   float* __restrict__ pdot) {
    int wv = (blockIdx.x * blockDim.x + threadIdx.x) >> 6;
    int lane = threadIdx.x & 63;
    int ns = lane >> 3, f = lane & 7;
    int node = wv * 8 + ns;
    bool valid = node < N_NODES;
    int nodec = valid ? node : 0;

    float di = dinv[nodec];
    const float4* L4 = (const float4*)(aggL + (size_t)nodec * 64 + f * 8);
    const float4* H4 = (const float4*)(aggH + (size_t)nodec * 64 + f * 8);
    float4 L0 = L4[0], L1 = L4[1];
    float4 H0 = H4[0], H1 = H4[1];
    uint4 su = *(const uint4*)((const char*)S + (size_t)nodec * 128 + f * 16);
    float4 bb0 = ((const float4*)b3)[2 * f];
    float4 bb1 = ((const float4*)b3)[2 * f + 1];
    float4 w0 = ((const float4*)Wl)[2 * f];
    float4 w1 = ((const float4*)Wl)[2 * f + 1];

    float d = 0.f;
    d += fmaxf(di * (L0.x + H0.x + bfl(su.x)) + bb0.x, 0.f) * w0.x;
    d += fmaxf(di * (L0.y + H0.y + bfh(su.x)) + bb0.y, 0.f) * w0.y;
    d += fmaxf(di * (L0.z + H0.z + bfl(su.y)) + bb0.z, 0.f) * w0.z;
    d += fmaxf(di * (L0.w + H0.w + bfh(su.y)) + bb0.w, 0.f) * w0.w;
    d += fmaxf(di * (L1.x + H1.x + bfl(su.z)) + bb1.x, 0.f) * w1.x;
    d += fmaxf(di * (L1.y + H1.y + bfh(su.z)) + bb1.y, 0.f) * w1.y;
    d += fmaxf(di * (L1.z + H1.z + bfl(su.w)) + bb1.z, 0.f) * w1.z;
    d += fmaxf(di * (L1.w + H1.w + bfh(su.w)) + bb1.w, 0.f) * w1.w;
#pragma unroll
    for (int m = 1; m <= 4; m <<= 1) d += __shfl_xor(d, m);
    if (valid && f == 0) pdot[node] = d;
}

// ---------------- final: per-graph mean of pdot + bias ----------------
__global__ __launch_bounds__(64) void final_out(const float* __restrict__ pdot,
                                                const int* __restrict__ batch,
                                                const float* __restrict__ bl,
                                                float* __restrict__ out) {
    int g = blockIdx.x;
    __shared__ int slo, shi;
    int lane = threadIdx.x;
    if (lane == 0) {
        int a = 0, b = N_NODES;
        while (a < b) { int m = (a + b) >> 1; if (batch[m] < g) a = m + 1; else b = m; }
        slo = a;
        b = N_NODES;
        while (a < b) { int m = (a + b) >> 1; if (batch[m] < g + 1) a = m + 1; else b = m; }
        shi = a;
    }
    __syncthreads();
    int lo = slo, hi = shi;
    float acc = 0.f;
    for (int i = lo + lane; i < hi; i += 64) acc += pdot[i];
#pragma unroll
    for (int off = 32; off > 0; off >>= 1) acc += __shfl_down(acc, off);
    if (lane == 0) {
        float cnt = (float)(hi - lo);
        out[g] = acc / fmaxf(cnt, 1.0f) + bl[0];
    }
}

extern "C" void kernel_launch(void* const* d_in, const int* in_sizes, int n_in,
                              void* d_out, int out_size, void* d_ws, size_t ws_size,
                              hipStream_t stream) {
    const float* x     = (const float*)d_in[0];
    const int*   src   = (const int*)d_in[1];
    const int*   dst   = (const int*)d_in[2];
    const int*   batch = (const int*)d_in[3];
    const float* W1 = (const float*)d_in[4];  const float* b1 = (const float*)d_in[5];
    const float* W2 = (const float*)d_in[6];  const float* b2 = (const float*)d_in[7];
    const float* W3 = (const float*)d_in[8];  const float* b3 = (const float*)d_in[9];
    const float* Wl = (const float*)d_in[10]; const float* bl = (const float*)d_in[11];
    float* out = (float*)d_out;

    char* ws = (char*)d_ws;
    unsigned short* S = (unsigned short*)ws;                         // (N+1)*64 bf16 scaled table
    float* aggL   = (float*)(S + (size_t)(N_NODES + 1) * F);         // N*64 f32 low partials
    float* aggH   = aggL + (size_t)N_NODES * F;                      // N*64 f32 high partials
    float* dinv   = aggH + (size_t)N_NODES * F;                      // N
    float* pdot   = dinv + N_NODES;                                  // N
    int*   rbegL  = (int*)(pdot + N_NODES);                          // N
    int*   rendL  = rbegL + N_NODES;                                 // N
    int*   rbegH  = rendL + N_NODES;                                 // N
    int*   rendH  = rbegH + N_NODES;                                 // N
    int*   bcur   = rendH + N_NODES;                                 // NBUCK
    unsigned int* bpair = (unsigned int*)(bcur + NBUCK);             // NBUCK*CAP
    int*   eidx   = (int*)(bpair + (size_t)NBUCK * CAP);             // NBUCK*CAP

    const int GEMM_GRID = (N_NODES + 127) / 128;                     // 391

    // ---- preprocessing: padded split-CSR build ----
    hipMemsetAsync(bcur, 0, NBUCK * sizeof(int), stream);
    partition_edges<<<P3_GRID, 256, 0, stream>>>(src, dst, bcur, bpair);
    bucket_sort<<<NBUCK, 256, 0, stream>>>(bpair, bcur, eidx, rbegL, rendL, rbegH, rendH, dinv, S);

    // ---- layer 1 ----
    gemm64_t<0><<<GEMM_GRID, 256, 0, stream>>>(x, nullptr, nullptr, nullptr, nullptr, W1, dinv, S, N_NODES);
    gather_split<<<GATHER_GRID, 256, 0, stream>>>(rbegL, rendL, rbegH, rendH, eidx, S, aggL, aggH);

    // ---- layer 2 (h-fold of layer-1 partials in the GEMM loader) ----
    gemm64_t<1><<<GEMM_GRID, 256, 0, stream>>>(nullptr, aggL, aggH, S, b1, W2, dinv, S, N_NODES);
    gather_split<<<GATHER_GRID, 256, 0, stream>>>(rbegL, rendL, rbegH, rendH, eidx, S, aggL, aggH);

    // ---- layer 3 ----
    gemm64_t<1><<<GEMM_GRID, 256, 0, stream>>>(nullptr, aggL, aggH, S, b2, W3, dinv, S, N_NODES);
    gather_split<<<GATHER_GRID, 256, 0, stream>>>(rbegL, rendL, rbegH, rendH, eidx, S, aggL, aggH);

    // ---- layer-3 finalize + pooling dot, then per-graph mean ----
    pdot_kernel<<<PDOT_GRID, 256, 0, stream>>>(aggL, aggH, S, dinv, b3, Wl, pdot);
    final_out<<<N_GRAPHS, 64, 0, stream>>>(pdot, batch, bl, out);
}